// Round 4
// baseline (5338.155 us; speedup 1.0000x reference)
//
#include <hip/hip_runtime.h>

#define N_USERS 100000
#define N_ITEMS 50000
#define N_TOPICS 1000
#define N_NODES (N_USERS + N_ITEMS + N_TOPICS)   // 151000
#define DIM 64
#define NNZ 4000000
#define BATCH 16384

#define BROWS 128                                 // rows per bucket
#define NB ((N_NODES + BROWS - 1) / BROWS)        // 1180 buckets
#define NGRP 8                                    // XCD groups for scatter

// ---------------------------------------------------------------------------
// Build X0 = concat(user_w, item_w, topic_w). One float4 (4 dims) per thread.
// ---------------------------------------------------------------------------
__global__ void concat_init(const float4* __restrict__ uw,
                            const float4* __restrict__ iw,
                            const float4* __restrict__ tw,
                            float4* __restrict__ x0) {
    int tid = blockIdx.x * blockDim.x + threadIdx.x;   // node*16 + q
    const int total = N_NODES * (DIM / 4);
    if (tid >= total) return;
    int node = tid >> 4;
    int q = tid & 15;
    float4 v;
    if (node < N_USERS)                v = uw[node * 16 + q];
    else if (node < N_USERS + N_ITEMS) v = iw[(node - N_USERS) * 16 + q];
    else                               v = tw[(node - N_USERS - N_ITEMS) * 16 + q];
    x0[tid] = v;
}

// ---------------------------------------------------------------------------
// Bucket histogram: per-block LDS histogram (NB ints), one global flush/block.
// ---------------------------------------------------------------------------
__global__ void bucket_hist(const int* __restrict__ row, int* __restrict__ bcnt) {
    __shared__ int h[NB];
    for (int i = threadIdx.x; i < NB; i += 256) h[i] = 0;
    __syncthreads();
    int stride = gridDim.x * 256;
    for (int e = blockIdx.x * 256 + threadIdx.x; e < NNZ; e += stride) {
        int r = __builtin_nontemporal_load(&row[e]);
        atomicAdd(&h[r >> 7], 1);
    }
    __syncthreads();
    for (int i = threadIdx.x; i < NB; i += 256) {
        int v = h[i];
        if (v) atomicAdd(&bcnt[i], v);
    }
}

// ---------------------------------------------------------------------------
// Exclusive scan over NB bucket counts (single block, wave-shfl + LDS).
// ---------------------------------------------------------------------------
__global__ void bucket_scan(const int* __restrict__ bcnt,
                            int* __restrict__ bptr,
                            int* __restrict__ bcur) {
    __shared__ int wsum[16];
    __shared__ int carry_s;
    const int t = threadIdx.x;
    const int lane = t & 63;
    const int wid = t >> 6;
    if (t == 0) carry_s = 0;
    __syncthreads();
    for (int base = 0; base < NB; base += 1024) {
        int i = base + t;
        int v = (i < NB) ? bcnt[i] : 0;
        int x = v;
        #pragma unroll
        for (int off = 1; off < 64; off <<= 1) {
            int y = __shfl_up(x, off, 64);
            if (lane >= off) x += y;
        }
        if (lane == 63) wsum[wid] = x;
        __syncthreads();
        int wbase = 0;
        for (int w = 0; w < wid; ++w) wbase += wsum[w];
        int excl = carry_s + wbase + (x - v);
        if (i < NB) { bptr[i] = excl; bcur[i] = excl; }
        __syncthreads();
        if (t == 1023) carry_s = excl + v;
        __syncthreads();
    }
    if (t == 0) bptr[NB] = NNZ;
}

// ---------------------------------------------------------------------------
// Binning scatter, XCD-partitioned. Concurrent writes to a bucket are
// contiguous at its cursor frontier -> ~147 hot lines per XCD L2 -> stores
// merge to full lines. Streams read nontemporal (no L2 pollution).
// Payload: ((r&127)<<18)|col , val   (col < 2^18).
// ---------------------------------------------------------------------------
__global__ void bin_scatter(const int* __restrict__ row,
                            const int* __restrict__ col,
                            const float* __restrict__ vals,
                            int* __restrict__ bcur,
                            int2* __restrict__ cv) {
    int grp = blockIdx.x & (NGRP - 1);
    int chunk = blockIdx.x >> 3;
    int e = chunk * 256 + threadIdx.x;
    if (e >= NNZ) return;
    int r = __builtin_nontemporal_load(&row[e]);
    int b = r >> 7;
    if ((b & (NGRP - 1)) != grp) return;
    int c = __builtin_nontemporal_load(&col[e]);
    float v = __builtin_nontemporal_load(&vals[e]);
    int p = atomicAdd(&bcur[b], 1);
    cv[p] = make_int2(((r & (BROWS - 1)) << 18) | c, __float_as_int(v));
}

// ---------------------------------------------------------------------------
// SpMM over bucketed COO: one block (4 waves) per bucket. 32 KB LDS float
// accumulator [128 rows x 64 dims]; lane = dim; ds_add_f32 per edge;
// coalesced float4 write-out. Edge order within bucket irrelevant.
// ---------------------------------------------------------------------------
__global__ void __launch_bounds__(256)
spmm_bucket(const int* __restrict__ bptr,
            const int2* __restrict__ cv,
            const float* __restrict__ x,
            float* __restrict__ y) {
    __shared__ float acc[BROWS * DIM];   // 32 KB
    const int t = threadIdx.x;
    const int lane = t & 63;
    const int w = t >> 6;
    const int b = blockIdx.x;

    #pragma unroll 4
    for (int i = t; i < BROWS * DIM; i += 256) acc[i] = 0.0f;
    __syncthreads();

    int beg = bptr[b];
    int end = bptr[b + 1];
    int n = end - beg;
    int wbeg = beg + (n * w) / 4;
    int wend = beg + (n * (w + 1)) / 4;

    int j = wbeg;
    for (; j + 3 < wend; j += 4) {
        int2 e0 = cv[j];
        int2 e1 = cv[j + 1];
        int2 e2 = cv[j + 2];
        int2 e3 = cv[j + 3];
        float x0 = x[(size_t)(e0.x & 0x3FFFF) * 64 + lane];
        float x1 = x[(size_t)(e1.x & 0x3FFFF) * 64 + lane];
        float x2 = x[(size_t)(e2.x & 0x3FFFF) * 64 + lane];
        float x3 = x[(size_t)(e3.x & 0x3FFFF) * 64 + lane];
        atomicAdd(&acc[((e0.x >> 18) << 6) + lane], __int_as_float(e0.y) * x0);
        atomicAdd(&acc[((e1.x >> 18) << 6) + lane], __int_as_float(e1.y) * x1);
        atomicAdd(&acc[((e2.x >> 18) << 6) + lane], __int_as_float(e2.y) * x2);
        atomicAdd(&acc[((e3.x >> 18) << 6) + lane], __int_as_float(e3.y) * x3);
    }
    for (; j < wend; ++j) {
        int2 e0 = cv[j];
        float x0 = x[(size_t)(e0.x & 0x3FFFF) * 64 + lane];
        atomicAdd(&acc[((e0.x >> 18) << 6) + lane], __int_as_float(e0.y) * x0);
    }
    __syncthreads();

    // coalesced write-out (float4), guard the last (partial) bucket
    int rowbase = b * BROWS;
    int maxr = N_NODES - rowbase;
    int nf4 = ((maxr >= BROWS) ? BROWS : maxr) * (DIM / 4);
    float4* y4 = (float4*)(y + (size_t)rowbase * DIM);
    const float4* a4 = (const float4*)acc;
    for (int i = t; i < nf4; i += 256) y4[i] = a4[i];
}

// ---------------------------------------------------------------------------
// Batch accumulator init: accb[b] = user_w[users[b]], accb[B+b] = item_w[items[b]]
// ---------------------------------------------------------------------------
__global__ void batch_init(const float4* __restrict__ uw,
                           const float4* __restrict__ iw,
                           const int* __restrict__ users,
                           const int* __restrict__ items,
                           float4* __restrict__ accb) {
    int tid = blockIdx.x * blockDim.x + threadIdx.x;   // row*16 + q
    const int total = 2 * BATCH * (DIM / 4);
    if (tid >= total) return;
    int r = tid >> 4;
    int q = tid & 15;
    float4 v;
    if (r < BATCH) v = uw[(size_t)users[r] * 16 + q];
    else           v = iw[(size_t)items[r - BATCH] * 16 + q];
    accb[tid] = v;
}

// ---------------------------------------------------------------------------
// Batch accumulator add from full node table.
// ---------------------------------------------------------------------------
__global__ void batch_add(const float4* __restrict__ emb,
                          const int* __restrict__ users,
                          const int* __restrict__ items,
                          float4* __restrict__ accb) {
    int tid = blockIdx.x * blockDim.x + threadIdx.x;
    const int total = 2 * BATCH * (DIM / 4);
    if (tid >= total) return;
    int r = tid >> 4;
    int q = tid & 15;
    int node = (r < BATCH) ? users[r] : (N_USERS + items[r - BATCH]);
    float4 v = emb[(size_t)node * 16 + q];
    float4 a = accb[tid];
    a.x += v.x; a.y += v.y; a.z += v.z; a.w += v.w;
    accb[tid] = a;
}

// ---------------------------------------------------------------------------
// Final dot: out[b] = (accb[b] . accb[BATCH+b]) / 16
// ---------------------------------------------------------------------------
__global__ void final_dot(const float* __restrict__ accb,
                          float* __restrict__ out) {
    int b = blockIdx.x * 4 + (threadIdx.x >> 6);
    int lane = threadIdx.x & 63;
    if (b >= BATCH) return;
    float pu = accb[(size_t)b * 64 + lane];
    float pi = accb[(size_t)(BATCH + b) * 64 + lane];
    float p = pu * pi;
    #pragma unroll
    for (int off = 32; off > 0; off >>= 1)
        p += __shfl_down(p, off, 64);
    if (lane == 0) out[b] = p * (1.0f / 16.0f);
}

extern "C" void kernel_launch(void* const* d_in, const int* in_sizes, int n_in,
                              void* d_out, int out_size, void* d_ws, size_t ws_size,
                              hipStream_t stream) {
    const float* uw   = (const float*)d_in[0];
    const float* iw   = (const float*)d_in[1];
    const float* tw   = (const float*)d_in[2];
    const float* vals = (const float*)d_in[3];
    const int*   row  = (const int*)d_in[4];
    const int*   col  = (const int*)d_in[5];
    const int*   users= (const int*)d_in[6];
    const int*   items= (const int*)d_in[7];
    float* out = (float*)d_out;

    // ---- workspace layout ----
    char* ws = (char*)d_ws;
    const size_t NODE_F = (size_t)N_NODES * DIM;       // 9,664,000 floats
    float* A    = (float*)ws;  ws += NODE_F * 4;
    float* B    = (float*)ws;  ws += NODE_F * 4;
    float* ACCB = (float*)ws;  ws += (size_t)2 * BATCH * DIM * 4;
    int*   bcnt = (int*)ws;    ws += (size_t)NB * 4;
    int*   bptr = (int*)ws;    ws += (size_t)(NB + 1) * 4;
    int*   bcur = (int*)ws;    ws += (size_t)NB * 4;
    int2*  cv   = (int2*)ws;   ws += (size_t)NNZ * 8;

    const int node_v4  = N_NODES * (DIM / 4);
    const int batch_v4 = 2 * BATCH * (DIM / 4);

    // ---- bucketed-COO build ----
    hipMemsetAsync(bcnt, 0, (size_t)NB * 4, stream);
    bucket_hist<<<512, 256, 0, stream>>>(row, bcnt);
    bucket_scan<<<1, 1024, 0, stream>>>(bcnt, bptr, bcur);
    bin_scatter<<<NGRP * ((NNZ + 255) / 256), 256, 0, stream>>>(
        row, col, vals, bcur, cv);

    // ---- layer-0 embedding + batch accumulator init ----
    concat_init<<<(node_v4 + 255) / 256, 256, 0, stream>>>(
        (const float4*)uw, (const float4*)iw, (const float4*)tw, (float4*)A);
    batch_init<<<(batch_v4 + 255) / 256, 256, 0, stream>>>(
        (const float4*)uw, (const float4*)iw, users, items, (float4*)ACCB);

    // ---- 3 propagation layers ----
    float* cur = A;
    float* nxt = B;
    for (int l = 0; l < 3; ++l) {
        spmm_bucket<<<NB, 256, 0, stream>>>(bptr, cv, cur, nxt);
        batch_add<<<(batch_v4 + 255) / 256, 256, 0, stream>>>(
            (const float4*)nxt, users, items, (float4*)ACCB);
        float* t = cur; cur = nxt; nxt = t;
    }

    final_dot<<<(BATCH + 3) / 4, 256, 0, stream>>>(ACCB, out);
}

// Round 6
// 1550.020 us; speedup vs baseline: 3.4439x; 3.4439x over previous
//
#include <hip/hip_runtime.h>

#define N_USERS 100000
#define N_ITEMS 50000
#define N_TOPICS 1000
#define N_NODES (N_USERS + N_ITEMS + N_TOPICS)   // 151000
#define DIM 64
#define NNZ 4000000
#define BATCH 16384

#define BROWS 128                                 // rows per bucket
#define NB ((N_NODES + BROWS - 1) / BROWS)        // 1180 buckets
#define NGRP 8                                    // XCD groups for scatter

// ---------------------------------------------------------------------------
// Build X0 = concat(user_w, item_w, topic_w). One float4 (4 dims) per thread.
// ---------------------------------------------------------------------------
__global__ void concat_init(const float4* __restrict__ uw,
                            const float4* __restrict__ iw,
                            const float4* __restrict__ tw,
                            float4* __restrict__ x0) {
    int tid = blockIdx.x * blockDim.x + threadIdx.x;   // node*16 + q
    const int total = N_NODES * (DIM / 4);
    if (tid >= total) return;
    int node = tid >> 4;
    int q = tid & 15;
    float4 v;
    if (node < N_USERS)                v = uw[node * 16 + q];
    else if (node < N_USERS + N_ITEMS) v = iw[(node - N_USERS) * 16 + q];
    else                               v = tw[(node - N_USERS - N_ITEMS) * 16 + q];
    x0[tid] = v;
}

// ---------------------------------------------------------------------------
// Bucket histogram: per-block LDS histogram (NB ints), one global flush/block.
// ---------------------------------------------------------------------------
__global__ void bucket_hist(const int* __restrict__ row, int* __restrict__ bcnt) {
    __shared__ int h[NB];
    for (int i = threadIdx.x; i < NB; i += 256) h[i] = 0;
    __syncthreads();
    int stride = gridDim.x * 256;
    for (int e = blockIdx.x * 256 + threadIdx.x; e < NNZ; e += stride) {
        int r = __builtin_nontemporal_load(&row[e]);
        atomicAdd(&h[r >> 7], 1);
    }
    __syncthreads();
    for (int i = threadIdx.x; i < NB; i += 256) {
        int v = h[i];
        if (v) atomicAdd(&bcnt[i], v);
    }
}

// ---------------------------------------------------------------------------
// Exclusive scan over NB bucket counts (single block, wave-shfl + LDS).
// ---------------------------------------------------------------------------
__global__ void bucket_scan(const int* __restrict__ bcnt,
                            int* __restrict__ bptr,
                            int* __restrict__ bcur,
                            int* __restrict__ rowptr) {
    __shared__ int wsum[16];
    __shared__ int carry_s;
    const int t = threadIdx.x;
    const int lane = t & 63;
    const int wid = t >> 6;
    if (t == 0) carry_s = 0;
    __syncthreads();
    for (int base = 0; base < NB; base += 1024) {
        int i = base + t;
        int v = (i < NB) ? bcnt[i] : 0;
        int x = v;
        #pragma unroll
        for (int off = 1; off < 64; off <<= 1) {
            int y = __shfl_up(x, off, 64);
            if (lane >= off) x += y;
        }
        if (lane == 63) wsum[wid] = x;
        __syncthreads();
        int wbase = 0;
        for (int w = 0; w < wid; ++w) wbase += wsum[w];
        int excl = carry_s + wbase + (x - v);
        if (i < NB) { bptr[i] = excl; bcur[i] = excl; }
        __syncthreads();
        if (t == 1023) carry_s = excl + v;
        __syncthreads();
    }
    if (t == 0) { bptr[NB] = NNZ; rowptr[N_NODES] = NNZ; }
}

// ---------------------------------------------------------------------------
// Binning scatter, XCD-partitioned: bucket b is owned by group (b&7); under
// round-robin block->XCD dispatch each bucket's write frontier lives in ONE
// XCD's L2 (147 frontiers/XCD ~ 9 KB hot lines) -> stores merge to full
// lines. Streams read nontemporal. Payload: ((r&127)<<18)|col , val.
// ---------------------------------------------------------------------------
__global__ void bin_scatter(const int* __restrict__ row,
                            const int* __restrict__ col,
                            const float* __restrict__ vals,
                            int* __restrict__ bcur,
                            int2* __restrict__ cvtmp) {
    int grp = blockIdx.x & (NGRP - 1);
    int chunk = blockIdx.x >> 3;
    int e = chunk * 256 + threadIdx.x;
    if (e >= NNZ) return;
    int r = __builtin_nontemporal_load(&row[e]);
    int b = r >> 7;
    if ((b & (NGRP - 1)) != grp) return;
    int c = __builtin_nontemporal_load(&col[e]);
    float v = __builtin_nontemporal_load(&vals[e]);
    int p = atomicAdd(&bcur[b], 1);
    cvtmp[p] = make_int2(((r & (BROWS - 1)) << 18) | c, __float_as_int(v));
}

// ---------------------------------------------------------------------------
// Bucket-local counting sort -> row-sorted CSR (cv) + rowptr.
// One block per bucket; 128 LDS counters/cursors; two streaming passes over
// the bucket's ~27 KB edge segment. Edge records loaded as 8B long long
// (nontemporal builtin rejects HIP vector types).
// ---------------------------------------------------------------------------
__global__ void __launch_bounds__(256)
bucket_sort(const int* __restrict__ bptr,
            const long long* __restrict__ cvtmp,
            int2* __restrict__ cv,
            int* __restrict__ rowptr) {
    __shared__ int cnt[BROWS];
    __shared__ int cur[BROWS];
    const int t = threadIdx.x;
    const int b = blockIdx.x;
    const int beg = bptr[b];
    const int end = bptr[b + 1];

    for (int i = t; i < BROWS; i += 256) cnt[i] = 0;
    __syncthreads();

    // pass 1: per-row counts (key = bits 18..24 of low word)
    for (int j = beg + t; j < end; j += 256) {
        long long e = __builtin_nontemporal_load(&cvtmp[j]);
        int key = ((int)e >> 18) & (BROWS - 1);
        atomicAdd(&cnt[key], 1);
    }
    __syncthreads();

    // exclusive scan of 128 counts on wave 0; also emit rowptr
    if (t < 64) {
        int lane = t;
        int v0 = cnt[lane];
        int v1 = cnt[64 + lane];
        int x0 = v0;
        #pragma unroll
        for (int off = 1; off < 64; off <<= 1) {
            int y = __shfl_up(x0, off, 64);
            if (lane >= off) x0 += y;
        }
        int tot0 = __shfl(x0, 63, 64);
        int x1 = v1;
        #pragma unroll
        for (int off = 1; off < 64; off <<= 1) {
            int y = __shfl_up(x1, off, 64);
            if (lane >= off) x1 += y;
        }
        x1 += tot0;
        int e0 = x0 - v0;
        int e1 = x1 - v1;
        cur[lane] = e0;
        cur[64 + lane] = e1;
        int rowbase = b * BROWS;
        if (rowbase + lane < N_NODES)      rowptr[rowbase + lane] = beg + e0;
        if (rowbase + 64 + lane < N_NODES) rowptr[rowbase + 64 + lane] = beg + e1;
    }
    __syncthreads();

    // pass 2: scatter into row-sorted order, strip row bits
    for (int j = beg + t; j < end; j += 256) {
        long long e = __builtin_nontemporal_load(&cvtmp[j]);
        int lo = (int)e;
        int hi = (int)(e >> 32);
        int key = (lo >> 18) & (BROWS - 1);
        int p = atomicAdd(&cur[key], 1);
        cv[beg + p] = make_int2(lo & 0x3FFFF, hi);
    }
}

// ---------------------------------------------------------------------------
// SpMM over CSR: one 64-lane wave per row, lane = dim, register acc, no LDS.
// ---------------------------------------------------------------------------
__global__ void spmm_csr(const int* __restrict__ rowptr,
                         const int2* __restrict__ cv,
                         const float* __restrict__ x,
                         float* __restrict__ y) {
    int r = blockIdx.x * 4 + (threadIdx.x >> 6);
    int lane = threadIdx.x & 63;
    if (r >= N_NODES) return;
    int beg = rowptr[r];
    int end = rowptr[r + 1];
    float acc0 = 0.0f, acc1 = 0.0f;
    int j = beg;
    for (; j + 7 < end; j += 8) {
        #pragma unroll
        for (int k = 0; k < 8; k += 2) {
            int2 ea = cv[j + k];
            int2 eb = cv[j + k + 1];
            float xa = x[(size_t)ea.x * 64 + lane];
            float xb = x[(size_t)eb.x * 64 + lane];
            acc0 = fmaf(__int_as_float(ea.y), xa, acc0);
            acc1 = fmaf(__int_as_float(eb.y), xb, acc1);
        }
    }
    for (; j < end; ++j) {
        int2 e = cv[j];
        acc0 = fmaf(__int_as_float(e.y), x[(size_t)e.x * 64 + lane], acc0);
    }
    y[(size_t)r * 64 + lane] = acc0 + acc1;
}

// ---------------------------------------------------------------------------
// Layer-3 SpMM restricted to batch rows: one wave per batch entry,
// accumulating straight into ACCB (only these rows are ever read).
// ~870K edges instead of 4M.
// ---------------------------------------------------------------------------
__global__ void spmm_batch(const int* __restrict__ rowptr,
                           const int2* __restrict__ cv,
                           const float* __restrict__ x,
                           const int* __restrict__ users,
                           const int* __restrict__ items,
                           float* __restrict__ accb) {
    int b = blockIdx.x * 4 + (threadIdx.x >> 6);
    int lane = threadIdx.x & 63;
    if (b >= 2 * BATCH) return;
    int r = (b < BATCH) ? users[b] : (N_USERS + items[b - BATCH]);
    int beg = rowptr[r];
    int end = rowptr[r + 1];
    float acc0 = 0.0f, acc1 = 0.0f;
    int j = beg;
    for (; j + 7 < end; j += 8) {
        #pragma unroll
        for (int k = 0; k < 8; k += 2) {
            int2 ea = cv[j + k];
            int2 eb = cv[j + k + 1];
            float xa = x[(size_t)ea.x * 64 + lane];
            float xb = x[(size_t)eb.x * 64 + lane];
            acc0 = fmaf(__int_as_float(ea.y), xa, acc0);
            acc1 = fmaf(__int_as_float(eb.y), xb, acc1);
        }
    }
    for (; j < end; ++j) {
        int2 e = cv[j];
        acc0 = fmaf(__int_as_float(e.y), x[(size_t)e.x * 64 + lane], acc0);
    }
    size_t o = (size_t)b * 64 + lane;
    accb[o] += acc0 + acc1;
}

// ---------------------------------------------------------------------------
// Batch accumulator init: accb[b] = user_w[users[b]], accb[B+b] = item_w[items[b]]
// ---------------------------------------------------------------------------
__global__ void batch_init(const float4* __restrict__ uw,
                           const float4* __restrict__ iw,
                           const int* __restrict__ users,
                           const int* __restrict__ items,
                           float4* __restrict__ accb) {
    int tid = blockIdx.x * blockDim.x + threadIdx.x;   // row*16 + q
    const int total = 2 * BATCH * (DIM / 4);
    if (tid >= total) return;
    int r = tid >> 4;
    int q = tid & 15;
    float4 v;
    if (r < BATCH) v = uw[(size_t)users[r] * 16 + q];
    else           v = iw[(size_t)items[r - BATCH] * 16 + q];
    accb[tid] = v;
}

// ---------------------------------------------------------------------------
// Batch accumulator add from full node table (layers 1,2).
// ---------------------------------------------------------------------------
__global__ void batch_add(const float4* __restrict__ emb,
                          const int* __restrict__ users,
                          const int* __restrict__ items,
                          float4* __restrict__ accb) {
    int tid = blockIdx.x * blockDim.x + threadIdx.x;
    const int total = 2 * BATCH * (DIM / 4);
    if (tid >= total) return;
    int r = tid >> 4;
    int q = tid & 15;
    int node = (r < BATCH) ? users[r] : (N_USERS + items[r - BATCH]);
    float4 v = emb[(size_t)node * 16 + q];
    float4 a = accb[tid];
    a.x += v.x; a.y += v.y; a.z += v.z; a.w += v.w;
    accb[tid] = a;
}

// ---------------------------------------------------------------------------
// Final dot: out[b] = (accb[b] . accb[BATCH+b]) / 16
// ---------------------------------------------------------------------------
__global__ void final_dot(const float* __restrict__ accb,
                          float* __restrict__ out) {
    int b = blockIdx.x * 4 + (threadIdx.x >> 6);
    int lane = threadIdx.x & 63;
    if (b >= BATCH) return;
    float pu = accb[(size_t)b * 64 + lane];
    float pi = accb[(size_t)(BATCH + b) * 64 + lane];
    float p = pu * pi;
    #pragma unroll
    for (int off = 32; off > 0; off >>= 1)
        p += __shfl_down(p, off, 64);
    if (lane == 0) out[b] = p * (1.0f / 16.0f);
}

extern "C" void kernel_launch(void* const* d_in, const int* in_sizes, int n_in,
                              void* d_out, int out_size, void* d_ws, size_t ws_size,
                              hipStream_t stream) {
    const float* uw   = (const float*)d_in[0];
    const float* iw   = (const float*)d_in[1];
    const float* tw   = (const float*)d_in[2];
    const float* vals = (const float*)d_in[3];
    const int*   row  = (const int*)d_in[4];
    const int*   col  = (const int*)d_in[5];
    const int*   users= (const int*)d_in[6];
    const int*   items= (const int*)d_in[7];
    float* out = (float*)d_out;

    // ---- workspace layout ----
    char* ws = (char*)d_ws;
    const size_t NODE_F = (size_t)N_NODES * DIM;       // 9,664,000 floats
    float* A      = (float*)ws;  ws += NODE_F * 4;     // also reused as cvtmp
    float* B      = (float*)ws;  ws += NODE_F * 4;
    float* ACCB   = (float*)ws;  ws += (size_t)2 * BATCH * DIM * 4;
    int*   bcnt   = (int*)ws;    ws += (size_t)NB * 4;
    int*   bptr   = (int*)ws;    ws += (size_t)(NB + 1) * 4;
    int*   bcur   = (int*)ws;    ws += (size_t)NB * 4;
    int*   rowptr = (int*)ws;    ws += (size_t)(N_NODES + 1) * 4;
    int2*  cv     = (int2*)ws;   ws += (size_t)NNZ * 8;
    int2*  cvtmp  = (int2*)A;    // 32 MB staging inside A's 38.7 MB; done
                                 // before concat_init writes A (stream order)

    const int node_v4  = N_NODES * (DIM / 4);
    const int batch_v4 = 2 * BATCH * (DIM / 4);

    // ---- bucketed-COO build + bucket-local sort -> row-sorted CSR ----
    (void)hipMemsetAsync(bcnt, 0, (size_t)NB * 4, stream);
    bucket_hist<<<512, 256, 0, stream>>>(row, bcnt);
    bucket_scan<<<1, 1024, 0, stream>>>(bcnt, bptr, bcur, rowptr);
    bin_scatter<<<NGRP * ((NNZ + 255) / 256), 256, 0, stream>>>(
        row, col, vals, bcur, cvtmp);
    bucket_sort<<<NB, 256, 0, stream>>>(bptr, (const long long*)cvtmp, cv, rowptr);

    // ---- layer-0 embedding + batch accumulator init ----
    concat_init<<<(node_v4 + 255) / 256, 256, 0, stream>>>(
        (const float4*)uw, (const float4*)iw, (const float4*)tw, (float4*)A);
    batch_init<<<(batch_v4 + 255) / 256, 256, 0, stream>>>(
        (const float4*)uw, (const float4*)iw, users, items, (float4*)ACCB);

    // ---- layers 1,2: full SpMM; layer 3: batch rows only ----
    const int spmm_blocks = (N_NODES + 3) / 4;   // 4 row-waves per 256-block
    spmm_csr<<<spmm_blocks, 256, 0, stream>>>(rowptr, cv, A, B);
    batch_add<<<(batch_v4 + 255) / 256, 256, 0, stream>>>(
        (const float4*)B, users, items, (float4*)ACCB);
    spmm_csr<<<spmm_blocks, 256, 0, stream>>>(rowptr, cv, B, A);
    batch_add<<<(batch_v4 + 255) / 256, 256, 0, stream>>>(
        (const float4*)A, users, items, (float4*)ACCB);
    spmm_batch<<<(2 * BATCH + 3) / 4, 256, 0, stream>>>(
        rowptr, cv, A, users, items, ACCB);

    final_dot<<<(BATCH + 3) / 4, 256, 0, stream>>>(ACCB, out);
}

// Round 7
// 766.902 us; speedup vs baseline: 6.9607x; 2.0211x over previous
//
#include <hip/hip_runtime.h>

#define N_USERS 100000
#define N_ITEMS 50000
#define N_TOPICS 1000
#define N_NODES (N_USERS + N_ITEMS + N_TOPICS)   // 151000
#define DIM 64
#define NNZ 4000000
#define BATCH 16384

#define BROWS 128                                 // rows per bucket
#define NB ((N_NODES + BROWS - 1) / BROWS)        // 1180 buckets
#define NGRP 8                                    // XCD groups for scatter
#define GB ((NB + NGRP - 1) / NGRP)               // buckets per group = 148
#define CURPAD 16                                 // 1 cursor per 64B line

// ---------------------------------------------------------------------------
// Build X0 = concat(user_w, item_w, topic_w). One float4 (4 dims) per thread.
// ---------------------------------------------------------------------------
__global__ void concat_init(const float4* __restrict__ uw,
                            const float4* __restrict__ iw,
                            const float4* __restrict__ tw,
                            float4* __restrict__ x0) {
    int tid = blockIdx.x * blockDim.x + threadIdx.x;   // node*16 + q
    const int total = N_NODES * (DIM / 4);
    if (tid >= total) return;
    int node = tid >> 4;
    int q = tid & 15;
    float4 v;
    if (node < N_USERS)                v = uw[node * 16 + q];
    else if (node < N_USERS + N_ITEMS) v = iw[(node - N_USERS) * 16 + q];
    else                               v = tw[(node - N_USERS - N_ITEMS) * 16 + q];
    x0[tid] = v;
}

// ---------------------------------------------------------------------------
// Bucket histogram: per-block LDS histogram (NB ints), one global flush/block.
// ---------------------------------------------------------------------------
__global__ void bucket_hist(const int* __restrict__ row, int* __restrict__ bcnt) {
    __shared__ int h[NB];
    for (int i = threadIdx.x; i < NB; i += 256) h[i] = 0;
    __syncthreads();
    int stride = gridDim.x * 256;
    for (int e = blockIdx.x * 256 + threadIdx.x; e < NNZ; e += stride) {
        int r = __builtin_nontemporal_load(&row[e]);
        atomicAdd(&h[r >> 7], 1);
    }
    __syncthreads();
    for (int i = threadIdx.x; i < NB; i += 256) {
        int v = h[i];
        if (v) atomicAdd(&bcnt[i], v);
    }
}

// ---------------------------------------------------------------------------
// Exclusive scan over NB bucket counts (single block, wave-shfl + LDS).
// Cursors written PADDED (one per 64B line) to kill atomic false sharing.
// ---------------------------------------------------------------------------
__global__ void bucket_scan(const int* __restrict__ bcnt,
                            int* __restrict__ bptr,
                            int* __restrict__ bcur,
                            int* __restrict__ rowptr) {
    __shared__ int wsum[16];
    __shared__ int carry_s;
    const int t = threadIdx.x;
    const int lane = t & 63;
    const int wid = t >> 6;
    if (t == 0) carry_s = 0;
    __syncthreads();
    for (int base = 0; base < NB; base += 1024) {
        int i = base + t;
        int v = (i < NB) ? bcnt[i] : 0;
        int x = v;
        #pragma unroll
        for (int off = 1; off < 64; off <<= 1) {
            int y = __shfl_up(x, off, 64);
            if (lane >= off) x += y;
        }
        if (lane == 63) wsum[wid] = x;
        __syncthreads();
        int wbase = 0;
        for (int w = 0; w < wid; ++w) wbase += wsum[w];
        int excl = carry_s + wbase + (x - v);
        if (i < NB) { bptr[i] = excl; bcur[i * CURPAD] = excl; }
        __syncthreads();
        if (t == 1023) carry_s = excl + v;
        __syncthreads();
    }
    if (t == 0) { bptr[NB] = NNZ; rowptr[N_NODES] = NNZ; }
}

// ---------------------------------------------------------------------------
// Binning scatter, XCD-partitioned with CONTIGUOUS ownership: group g owns
// buckets [g*GB, (g+1)*GB). A group's cursors (padded, 1/line) and its cv
// destination region are contiguous -> no cross-XCD line ping-pong; ~148
// write frontiers stay resident in the owning XCD's L2 and merge to full
// lines. Streams read nontemporal. Payload: ((r&127)<<18)|col , val.
// ---------------------------------------------------------------------------
__global__ void bin_scatter(const int* __restrict__ row,
                            const int* __restrict__ col,
                            const float* __restrict__ vals,
                            int* __restrict__ bcur,
                            int2* __restrict__ cvtmp) {
    int grp = blockIdx.x & (NGRP - 1);
    int chunk = blockIdx.x >> 3;
    int e = chunk * 256 + threadIdx.x;
    if (e >= NNZ) return;
    int r = __builtin_nontemporal_load(&row[e]);
    int b = r >> 7;
    int lo = grp * GB;
    if (b < lo || b >= lo + GB) return;
    int c = __builtin_nontemporal_load(&col[e]);
    float v = __builtin_nontemporal_load(&vals[e]);
    int p = atomicAdd(&bcur[b * CURPAD], 1);
    cvtmp[p] = make_int2(((r & (BROWS - 1)) << 18) | c, __float_as_int(v));
}

// ---------------------------------------------------------------------------
// Bucket-local counting sort -> row-sorted CSR (cv) + rowptr.
// One block per bucket; 128 LDS counters/cursors; two streaming passes over
// the bucket's ~27 KB edge segment (L2-resident between passes).
// ---------------------------------------------------------------------------
__global__ void __launch_bounds__(256)
bucket_sort(const int* __restrict__ bptr,
            const long long* __restrict__ cvtmp,
            int2* __restrict__ cv,
            int* __restrict__ rowptr) {
    __shared__ int cnt[BROWS];
    __shared__ int cur[BROWS];
    const int t = threadIdx.x;
    const int b = blockIdx.x;
    const int beg = bptr[b];
    const int end = bptr[b + 1];

    for (int i = t; i < BROWS; i += 256) cnt[i] = 0;
    __syncthreads();

    // pass 1: per-row counts (key = bits 18..24 of low word)
    for (int j = beg + t; j < end; j += 256) {
        long long e = __builtin_nontemporal_load(&cvtmp[j]);
        int key = ((int)e >> 18) & (BROWS - 1);
        atomicAdd(&cnt[key], 1);
    }
    __syncthreads();

    // exclusive scan of 128 counts on wave 0; also emit rowptr
    if (t < 64) {
        int lane = t;
        int v0 = cnt[lane];
        int v1 = cnt[64 + lane];
        int x0 = v0;
        #pragma unroll
        for (int off = 1; off < 64; off <<= 1) {
            int y = __shfl_up(x0, off, 64);
            if (lane >= off) x0 += y;
        }
        int tot0 = __shfl(x0, 63, 64);
        int x1 = v1;
        #pragma unroll
        for (int off = 1; off < 64; off <<= 1) {
            int y = __shfl_up(x1, off, 64);
            if (lane >= off) x1 += y;
        }
        x1 += tot0;
        int e0 = x0 - v0;
        int e1 = x1 - v1;
        cur[lane] = e0;
        cur[64 + lane] = e1;
        int rowbase = b * BROWS;
        if (rowbase + lane < N_NODES)      rowptr[rowbase + lane] = beg + e0;
        if (rowbase + 64 + lane < N_NODES) rowptr[rowbase + 64 + lane] = beg + e1;
    }
    __syncthreads();

    // pass 2: scatter into row-sorted order, strip row bits
    for (int j = beg + t; j < end; j += 256) {
        long long e = __builtin_nontemporal_load(&cvtmp[j]);
        int lo = (int)e;
        int hi = (int)(e >> 32);
        int key = (lo >> 18) & (BROWS - 1);
        int p = atomicAdd(&cur[key], 1);
        cv[beg + p] = make_int2(lo & 0x3FFFF, hi);
    }
}

// ---------------------------------------------------------------------------
// SpMM over CSR: one 64-lane wave per row, lane = dim, register acc, no LDS.
// ---------------------------------------------------------------------------
__global__ void spmm_csr(const int* __restrict__ rowptr,
                         const int2* __restrict__ cv,
                         const float* __restrict__ x,
                         float* __restrict__ y) {
    int r = blockIdx.x * 4 + (threadIdx.x >> 6);
    int lane = threadIdx.x & 63;
    if (r >= N_NODES) return;
    int beg = rowptr[r];
    int end = rowptr[r + 1];
    float acc0 = 0.0f, acc1 = 0.0f;
    int j = beg;
    for (; j + 7 < end; j += 8) {
        #pragma unroll
        for (int k = 0; k < 8; k += 2) {
            int2 ea = cv[j + k];
            int2 eb = cv[j + k + 1];
            float xa = x[(size_t)ea.x * 64 + lane];
            float xb = x[(size_t)eb.x * 64 + lane];
            acc0 = fmaf(__int_as_float(ea.y), xa, acc0);
            acc1 = fmaf(__int_as_float(eb.y), xb, acc1);
        }
    }
    for (; j < end; ++j) {
        int2 e = cv[j];
        acc0 = fmaf(__int_as_float(e.y), x[(size_t)e.x * 64 + lane], acc0);
    }
    y[(size_t)r * 64 + lane] = acc0 + acc1;
}

// ---------------------------------------------------------------------------
// Layer-3 SpMM restricted to batch rows: one wave per batch entry,
// accumulating straight into ACCB (~870K edges instead of 4M).
// ---------------------------------------------------------------------------
__global__ void spmm_batch(const int* __restrict__ rowptr,
                           const int2* __restrict__ cv,
                           const float* __restrict__ x,
                           const int* __restrict__ users,
                           const int* __restrict__ items,
                           float* __restrict__ accb) {
    int b = blockIdx.x * 4 + (threadIdx.x >> 6);
    int lane = threadIdx.x & 63;
    if (b >= 2 * BATCH) return;
    int r = (b < BATCH) ? users[b] : (N_USERS + items[b - BATCH]);
    int beg = rowptr[r];
    int end = rowptr[r + 1];
    float acc0 = 0.0f, acc1 = 0.0f;
    int j = beg;
    for (; j + 7 < end; j += 8) {
        #pragma unroll
        for (int k = 0; k < 8; k += 2) {
            int2 ea = cv[j + k];
            int2 eb = cv[j + k + 1];
            float xa = x[(size_t)ea.x * 64 + lane];
            float xb = x[(size_t)eb.x * 64 + lane];
            acc0 = fmaf(__int_as_float(ea.y), xa, acc0);
            acc1 = fmaf(__int_as_float(eb.y), xb, acc1);
        }
    }
    for (; j < end; ++j) {
        int2 e = cv[j];
        acc0 = fmaf(__int_as_float(e.y), x[(size_t)e.x * 64 + lane], acc0);
    }
    size_t o = (size_t)b * 64 + lane;
    accb[o] += acc0 + acc1;
}

// ---------------------------------------------------------------------------
// Batch accumulator init: accb[b] = user_w[users[b]], accb[B+b] = item_w[items[b]]
// ---------------------------------------------------------------------------
__global__ void batch_init(const float4* __restrict__ uw,
                           const float4* __restrict__ iw,
                           const int* __restrict__ users,
                           const int* __restrict__ items,
                           float4* __restrict__ accb) {
    int tid = blockIdx.x * blockDim.x + threadIdx.x;   // row*16 + q
    const int total = 2 * BATCH * (DIM / 4);
    if (tid >= total) return;
    int r = tid >> 4;
    int q = tid & 15;
    float4 v;
    if (r < BATCH) v = uw[(size_t)users[r] * 16 + q];
    else           v = iw[(size_t)items[r - BATCH] * 16 + q];
    accb[tid] = v;
}

// ---------------------------------------------------------------------------
// Batch accumulator add from full node table (layers 1,2).
// ---------------------------------------------------------------------------
__global__ void batch_add(const float4* __restrict__ emb,
                          const int* __restrict__ users,
                          const int* __restrict__ items,
                          float4* __restrict__ accb) {
    int tid = blockIdx.x * blockDim.x + threadIdx.x;
    const int total = 2 * BATCH * (DIM / 4);
    if (tid >= total) return;
    int r = tid >> 4;
    int q = tid & 15;
    int node = (r < BATCH) ? users[r] : (N_USERS + items[r - BATCH]);
    float4 v = emb[(size_t)node * 16 + q];
    float4 a = accb[tid];
    a.x += v.x; a.y += v.y; a.z += v.z; a.w += v.w;
    accb[tid] = a;
}

// ---------------------------------------------------------------------------
// Final dot: out[b] = (accb[b] . accb[BATCH+b]) / 16
// ---------------------------------------------------------------------------
__global__ void final_dot(const float* __restrict__ accb,
                          float* __restrict__ out) {
    int b = blockIdx.x * 4 + (threadIdx.x >> 6);
    int lane = threadIdx.x & 63;
    if (b >= BATCH) return;
    float pu = accb[(size_t)b * 64 + lane];
    float pi = accb[(size_t)(BATCH + b) * 64 + lane];
    float p = pu * pi;
    #pragma unroll
    for (int off = 32; off > 0; off >>= 1)
        p += __shfl_down(p, off, 64);
    if (lane == 0) out[b] = p * (1.0f / 16.0f);
}

extern "C" void kernel_launch(void* const* d_in, const int* in_sizes, int n_in,
                              void* d_out, int out_size, void* d_ws, size_t ws_size,
                              hipStream_t stream) {
    const float* uw   = (const float*)d_in[0];
    const float* iw   = (const float*)d_in[1];
    const float* tw   = (const float*)d_in[2];
    const float* vals = (const float*)d_in[3];
    const int*   row  = (const int*)d_in[4];
    const int*   col  = (const int*)d_in[5];
    const int*   users= (const int*)d_in[6];
    const int*   items= (const int*)d_in[7];
    float* out = (float*)d_out;

    // ---- workspace layout ----
    char* ws = (char*)d_ws;
    const size_t NODE_F = (size_t)N_NODES * DIM;       // 9,664,000 floats
    float* A      = (float*)ws;  ws += NODE_F * 4;     // also reused as cvtmp
    float* B      = (float*)ws;  ws += NODE_F * 4;
    float* ACCB   = (float*)ws;  ws += (size_t)2 * BATCH * DIM * 4;
    int*   bcnt   = (int*)ws;    ws += (size_t)NB * 4;
    int*   bptr   = (int*)ws;    ws += (size_t)(NB + 1) * 4;
    int*   bcur   = (int*)ws;    ws += (size_t)NB * CURPAD * 4;   // padded
    int*   rowptr = (int*)ws;    ws += (size_t)(N_NODES + 1) * 4;
    int2*  cv     = (int2*)ws;   ws += (size_t)NNZ * 8;
    int2*  cvtmp  = (int2*)A;    // 32 MB staging inside A's 38.7 MB; done
                                 // before concat_init writes A (stream order)

    const int node_v4  = N_NODES * (DIM / 4);
    const int batch_v4 = 2 * BATCH * (DIM / 4);

    // ---- bucketed-COO build + bucket-local sort -> row-sorted CSR ----
    (void)hipMemsetAsync(bcnt, 0, (size_t)NB * 4, stream);
    bucket_hist<<<512, 256, 0, stream>>>(row, bcnt);
    bucket_scan<<<1, 1024, 0, stream>>>(bcnt, bptr, bcur, rowptr);
    bin_scatter<<<NGRP * ((NNZ + 255) / 256), 256, 0, stream>>>(
        row, col, vals, bcur, cvtmp);
    bucket_sort<<<NB, 256, 0, stream>>>(bptr, (const long long*)cvtmp, cv, rowptr);

    // ---- layer-0 embedding + batch accumulator init ----
    concat_init<<<(node_v4 + 255) / 256, 256, 0, stream>>>(
        (const float4*)uw, (const float4*)iw, (const float4*)tw, (float4*)A);
    batch_init<<<(batch_v4 + 255) / 256, 256, 0, stream>>>(
        (const float4*)uw, (const float4*)iw, users, items, (float4*)ACCB);

    // ---- layers 1,2: full SpMM; layer 3: batch rows only ----
    const int spmm_blocks = (N_NODES + 3) / 4;   // 4 row-waves per 256-block
    spmm_csr<<<spmm_blocks, 256, 0, stream>>>(rowptr, cv, A, B);
    batch_add<<<(batch_v4 + 255) / 256, 256, 0, stream>>>(
        (const float4*)B, users, items, (float4*)ACCB);
    spmm_csr<<<spmm_blocks, 256, 0, stream>>>(rowptr, cv, B, A);
    batch_add<<<(batch_v4 + 255) / 256, 256, 0, stream>>>(
        (const float4*)A, users, items, (float4*)ACCB);
    spmm_batch<<<(2 * BATCH + 3) / 4, 256, 0, stream>>>(
        rowptr, cv, A, users, items, ACCB);

    final_dot<<<(BATCH + 3) / 4, 256, 0, stream>>>(ACCB, out);
}

// Round 8
// 634.289 us; speedup vs baseline: 8.4160x; 1.2091x over previous
//
#include <hip/hip_runtime.h>

#define N_USERS 100000
#define N_ITEMS 50000
#define N_TOPICS 1000
#define N_NODES (N_USERS + N_ITEMS + N_TOPICS)   // 151000
#define DIM 64
#define NNZ 4000000
#define BATCH 16384

#define BROWS 128                                 // rows per bucket
#define NB ((N_NODES + BROWS - 1) / BROWS)        // 1180 buckets
#define NPART 512                                 // partition blocks
#define CHUNK ((NNZ + NPART - 1) / NPART)         // 7813 edges per block
#define SEGCAP 4608                               // LDS seg capacity (36 KB)

// ---------------------------------------------------------------------------
// Build X0 = concat(user_w, item_w, topic_w). One float4 (4 dims) per thread.
// ---------------------------------------------------------------------------
__global__ void concat_init(const float4* __restrict__ uw,
                            const float4* __restrict__ iw,
                            const float4* __restrict__ tw,
                            float4* __restrict__ x0) {
    int tid = blockIdx.x * blockDim.x + threadIdx.x;   // node*16 + q
    const int total = N_NODES * (DIM / 4);
    if (tid >= total) return;
    int node = tid >> 4;
    int q = tid & 15;
    float4 v;
    if (node < N_USERS)                v = uw[node * 16 + q];
    else if (node < N_USERS + N_ITEMS) v = iw[(node - N_USERS) * 16 + q];
    else                               v = tw[(node - N_USERS - N_ITEMS) * 16 + q];
    x0[tid] = v;
}

// ---------------------------------------------------------------------------
// Partition phase 1: per-block bucket histogram of its contiguous chunk.
// hcnt[g*NB + b] written coalesced. No global atomics.
// ---------------------------------------------------------------------------
__global__ void __launch_bounds__(256)
part_count(const int* __restrict__ row, int* __restrict__ hcnt) {
    __shared__ int h[NB];
    const int g = blockIdx.x;
    const int t = threadIdx.x;
    for (int i = t; i < NB; i += 256) h[i] = 0;
    __syncthreads();
    int e0 = g * CHUNK;
    int e1 = e0 + CHUNK; if (e1 > NNZ) e1 = NNZ;
    for (int e = e0 + t; e < e1; e += 256) {
        int r = __builtin_nontemporal_load(&row[e]);
        atomicAdd(&h[r >> 7], 1);
    }
    __syncthreads();
    int* dst = hcnt + (size_t)g * NB;
    for (int i = t; i < NB; i += 256) dst[i] = h[i];
}

// ---------------------------------------------------------------------------
// Partition phase 2a: per-bucket exclusive scan across the NPART blocks,
// in place; bucket totals -> bcnt. One 64-lane wave per bucket.
// ---------------------------------------------------------------------------
__global__ void part_scanA(int* __restrict__ hcnt, int* __restrict__ bcnt) {
    int b = blockIdx.x * 4 + (threadIdx.x >> 6);
    int lane = threadIdx.x & 63;
    if (b >= NB) return;
    int carry = 0;
    for (int base = 0; base < NPART; base += 64) {
        int g = base + lane;
        int v = hcnt[(size_t)g * NB + b];
        int x = v;
        #pragma unroll
        for (int off = 1; off < 64; off <<= 1) {
            int y = __shfl_up(x, off, 64);
            if (lane >= off) x += y;
        }
        int tot = __shfl(x, 63, 64);
        hcnt[(size_t)g * NB + b] = carry + x - v;
        carry += tot;
    }
    if (lane == 0) bcnt[b] = carry;
}

// ---------------------------------------------------------------------------
// Partition phase 2b: exclusive scan over NB bucket totals (single block).
// ---------------------------------------------------------------------------
__global__ void part_scanB(const int* __restrict__ bcnt,
                           int* __restrict__ bptr,
                           int* __restrict__ rowptr) {
    __shared__ int wsum[16];
    __shared__ int carry_s;
    const int t = threadIdx.x;
    const int lane = t & 63;
    const int wid = t >> 6;
    if (t == 0) carry_s = 0;
    __syncthreads();
    for (int base = 0; base < NB; base += 1024) {
        int i = base + t;
        int v = (i < NB) ? bcnt[i] : 0;
        int x = v;
        #pragma unroll
        for (int off = 1; off < 64; off <<= 1) {
            int y = __shfl_up(x, off, 64);
            if (lane >= off) x += y;
        }
        if (lane == 63) wsum[wid] = x;
        __syncthreads();
        int wbase = 0;
        for (int w = 0; w < wid; ++w) wbase += wsum[w];
        int excl = carry_s + wbase + (x - v);
        if (i < NB) bptr[i] = excl;
        __syncthreads();
        if (t == 1023) carry_s = excl + v;
        __syncthreads();
    }
    if (t == 0) { bptr[NB] = NNZ; rowptr[N_NODES] = NNZ; }
}

// ---------------------------------------------------------------------------
// Partition phase 3: atomic-free scatter. Block g re-reads its chunk; LDS
// cursors = bptr[b] + hcnt[g][b] give each (block,bucket) a deterministic
// disjoint destination run (avg 6.6 records, contiguous -> merges in L2).
// Zero global atomics. Payload: ((r&127)<<18)|col , val.
// ---------------------------------------------------------------------------
__global__ void __launch_bounds__(256)
part_scatter(const int* __restrict__ row,
             const int* __restrict__ col,
             const float* __restrict__ vals,
             const int* __restrict__ hcnt,
             const int* __restrict__ bptr,
             int2* __restrict__ cvtmp) {
    __shared__ int cur[NB];
    const int g = blockIdx.x;
    const int t = threadIdx.x;
    const int* hoff = hcnt + (size_t)g * NB;
    for (int i = t; i < NB; i += 256) cur[i] = bptr[i] + hoff[i];
    __syncthreads();
    int e0 = g * CHUNK;
    int e1 = e0 + CHUNK; if (e1 > NNZ) e1 = NNZ;
    for (int e = e0 + t; e < e1; e += 256) {
        int r = __builtin_nontemporal_load(&row[e]);
        int c = __builtin_nontemporal_load(&col[e]);
        float v = __builtin_nontemporal_load(&vals[e]);
        int p = atomicAdd(&cur[r >> 7], 1);
        cvtmp[p] = make_int2(((r & (BROWS - 1)) << 18) | c, __float_as_int(v));
    }
}

// ---------------------------------------------------------------------------
// Bucket-local counting sort -> row-sorted CSR (cv) + rowptr.
// Segment staged in LDS once (<=36 KB); count/scan/scatter from LDS; global
// two-pass fallback for oversized buckets (statistically never: mean 3390,
// sigma ~58, cap = +21 sigma).
// ---------------------------------------------------------------------------
__global__ void __launch_bounds__(256)
bucket_sort(const int* __restrict__ bptr,
            const long long* __restrict__ cvtmp,
            int2* __restrict__ cv,
            int* __restrict__ rowptr) {
    __shared__ int2 seg[SEGCAP];     // 36 KB
    __shared__ int cnt[BROWS];
    __shared__ int cur[BROWS];
    const int t = threadIdx.x;
    const int b = blockIdx.x;
    const int beg = bptr[b];
    const int end = bptr[b + 1];
    const int n = end - beg;

    for (int i = t; i < BROWS; i += 256) cnt[i] = 0;
    const bool lds_path = (n <= SEGCAP);

    if (lds_path) {
        for (int j = t; j < n; j += 256) {
            long long e = cvtmp[beg + j];
            seg[j] = make_int2((int)e, (int)(e >> 32));
        }
    }
    __syncthreads();

    // pass 1: per-row counts
    if (lds_path) {
        for (int j = t; j < n; j += 256)
            atomicAdd(&cnt[(seg[j].x >> 18) & (BROWS - 1)], 1);
    } else {
        for (int j = beg + t; j < end; j += 256) {
            long long e = cvtmp[j];
            atomicAdd(&cnt[((int)e >> 18) & (BROWS - 1)], 1);
        }
    }
    __syncthreads();

    // exclusive scan of 128 counts on wave 0; also emit rowptr
    if (t < 64) {
        int lane = t;
        int v0 = cnt[lane];
        int v1 = cnt[64 + lane];
        int x0 = v0;
        #pragma unroll
        for (int off = 1; off < 64; off <<= 1) {
            int y = __shfl_up(x0, off, 64);
            if (lane >= off) x0 += y;
        }
        int tot0 = __shfl(x0, 63, 64);
        int x1 = v1;
        #pragma unroll
        for (int off = 1; off < 64; off <<= 1) {
            int y = __shfl_up(x1, off, 64);
            if (lane >= off) x1 += y;
        }
        x1 += tot0;
        int e0 = x0 - v0;
        int e1 = x1 - v1;
        cur[lane] = e0;
        cur[64 + lane] = e1;
        int rowbase = b * BROWS;
        if (rowbase + lane < N_NODES)      rowptr[rowbase + lane] = beg + e0;
        if (rowbase + 64 + lane < N_NODES) rowptr[rowbase + 64 + lane] = beg + e1;
    }
    __syncthreads();

    // pass 2: scatter into row-sorted order, strip row bits
    if (lds_path) {
        for (int j = t; j < n; j += 256) {
            int2 e = seg[j];
            int p = atomicAdd(&cur[(e.x >> 18) & (BROWS - 1)], 1);
            cv[beg + p] = make_int2(e.x & 0x3FFFF, e.y);
        }
    } else {
        for (int j = beg + t; j < end; j += 256) {
            long long e = cvtmp[j];
            int lo = (int)e;
            int hi = (int)(e >> 32);
            int p = atomicAdd(&cur[(lo >> 18) & (BROWS - 1)], 1);
            cv[beg + p] = make_int2(lo & 0x3FFFF, hi);
        }
    }
}

// ---------------------------------------------------------------------------
// SpMM over CSR: one 64-lane wave per row, lane = dim, register acc, no LDS.
// ---------------------------------------------------------------------------
__global__ void spmm_csr(const int* __restrict__ rowptr,
                         const int2* __restrict__ cv,
                         const float* __restrict__ x,
                         float* __restrict__ y) {
    int r = blockIdx.x * 4 + (threadIdx.x >> 6);
    int lane = threadIdx.x & 63;
    if (r >= N_NODES) return;
    int beg = rowptr[r];
    int end = rowptr[r + 1];
    float acc0 = 0.0f, acc1 = 0.0f;
    int j = beg;
    for (; j + 7 < end; j += 8) {
        #pragma unroll
        for (int k = 0; k < 8; k += 2) {
            int2 ea = cv[j + k];
            int2 eb = cv[j + k + 1];
            float xa = x[(size_t)ea.x * 64 + lane];
            float xb = x[(size_t)eb.x * 64 + lane];
            acc0 = fmaf(__int_as_float(ea.y), xa, acc0);
            acc1 = fmaf(__int_as_float(eb.y), xb, acc1);
        }
    }
    for (; j < end; ++j) {
        int2 e = cv[j];
        acc0 = fmaf(__int_as_float(e.y), x[(size_t)e.x * 64 + lane], acc0);
    }
    y[(size_t)r * 64 + lane] = acc0 + acc1;
}

// ---------------------------------------------------------------------------
// Layer-3 SpMM restricted to batch rows: one wave per batch entry,
// accumulating straight into ACCB (~870K edges instead of 4M).
// ---------------------------------------------------------------------------
__global__ void spmm_batch(const int* __restrict__ rowptr,
                           const int2* __restrict__ cv,
                           const float* __restrict__ x,
                           const int* __restrict__ users,
                           const int* __restrict__ items,
                           float* __restrict__ accb) {
    int b = blockIdx.x * 4 + (threadIdx.x >> 6);
    int lane = threadIdx.x & 63;
    if (b >= 2 * BATCH) return;
    int r = (b < BATCH) ? users[b] : (N_USERS + items[b - BATCH]);
    int beg = rowptr[r];
    int end = rowptr[r + 1];
    float acc0 = 0.0f, acc1 = 0.0f;
    int j = beg;
    for (; j + 7 < end; j += 8) {
        #pragma unroll
        for (int k = 0; k < 8; k += 2) {
            int2 ea = cv[j + k];
            int2 eb = cv[j + k + 1];
            float xa = x[(size_t)ea.x * 64 + lane];
            float xb = x[(size_t)eb.x * 64 + lane];
            acc0 = fmaf(__int_as_float(ea.y), xa, acc0);
            acc1 = fmaf(__int_as_float(eb.y), xb, acc1);
        }
    }
    for (; j < end; ++j) {
        int2 e = cv[j];
        acc0 = fmaf(__int_as_float(e.y), x[(size_t)e.x * 64 + lane], acc0);
    }
    size_t o = (size_t)b * 64 + lane;
    accb[o] += acc0 + acc1;
}

// ---------------------------------------------------------------------------
// Batch accumulator init: accb[b] = user_w[users[b]], accb[B+b] = item_w[items[b]]
// ---------------------------------------------------------------------------
__global__ void batch_init(const float4* __restrict__ uw,
                           const float4* __restrict__ iw,
                           const int* __restrict__ users,
                           const int* __restrict__ items,
                           float4* __restrict__ accb) {
    int tid = blockIdx.x * blockDim.x + threadIdx.x;   // row*16 + q
    const int total = 2 * BATCH * (DIM / 4);
    if (tid >= total) return;
    int r = tid >> 4;
    int q = tid & 15;
    float4 v;
    if (r < BATCH) v = uw[(size_t)users[r] * 16 + q];
    else           v = iw[(size_t)items[r - BATCH] * 16 + q];
    accb[tid] = v;
}

// ---------------------------------------------------------------------------
// Batch accumulator add from full node table (layers 1,2).
// ---------------------------------------------------------------------------
__global__ void batch_add(const float4* __restrict__ emb,
                          const int* __restrict__ users,
                          const int* __restrict__ items,
                          float4* __restrict__ accb) {
    int tid = blockIdx.x * blockDim.x + threadIdx.x;
    const int total = 2 * BATCH * (DIM / 4);
    if (tid >= total) return;
    int r = tid >> 4;
    int q = tid & 15;
    int node = (r < BATCH) ? users[r] : (N_USERS + items[r - BATCH]);
    float4 v = emb[(size_t)node * 16 + q];
    float4 a = accb[tid];
    a.x += v.x; a.y += v.y; a.z += v.z; a.w += v.w;
    accb[tid] = a;
}

// ---------------------------------------------------------------------------
// Final dot: out[b] = (accb[b] . accb[BATCH+b]) / 16
// ---------------------------------------------------------------------------
__global__ void final_dot(const float* __restrict__ accb,
                          float* __restrict__ out) {
    int b = blockIdx.x * 4 + (threadIdx.x >> 6);
    int lane = threadIdx.x & 63;
    if (b >= BATCH) return;
    float pu = accb[(size_t)b * 64 + lane];
    float pi = accb[(size_t)(BATCH + b) * 64 + lane];
    float p = pu * pi;
    #pragma unroll
    for (int off = 32; off > 0; off >>= 1)
        p += __shfl_down(p, off, 64);
    if (lane == 0) out[b] = p * (1.0f / 16.0f);
}

extern "C" void kernel_launch(void* const* d_in, const int* in_sizes, int n_in,
                              void* d_out, int out_size, void* d_ws, size_t ws_size,
                              hipStream_t stream) {
    const float* uw   = (const float*)d_in[0];
    const float* iw   = (const float*)d_in[1];
    const float* tw   = (const float*)d_in[2];
    const float* vals = (const float*)d_in[3];
    const int*   row  = (const int*)d_in[4];
    const int*   col  = (const int*)d_in[5];
    const int*   users= (const int*)d_in[6];
    const int*   items= (const int*)d_in[7];
    float* out = (float*)d_out;

    // ---- workspace layout ----
    char* ws = (char*)d_ws;
    const size_t NODE_F = (size_t)N_NODES * DIM;       // 9,664,000 floats
    float* A      = (float*)ws;  ws += NODE_F * 4;     // also reused as cvtmp
    float* B      = (float*)ws;  ws += NODE_F * 4;
    float* ACCB   = (float*)ws;  ws += (size_t)2 * BATCH * DIM * 4;
    int*   bcnt   = (int*)ws;    ws += (size_t)NB * 4;
    int*   bptr   = (int*)ws;    ws += (size_t)(NB + 1) * 4;
    int*   rowptr = (int*)ws;    ws += (size_t)(N_NODES + 1) * 4;
    int*   hcnt   = (int*)ws;    ws += (size_t)NPART * NB * 4;   // 2.42 MB
    int2*  cv     = (int2*)ws;   ws += (size_t)NNZ * 8;
    int2*  cvtmp  = (int2*)A;    // 32 MB staging inside A's 38.7 MB; consumed
                                 // before concat_init writes A (stream order)

    const int node_v4  = N_NODES * (DIM / 4);
    const int batch_v4 = 2 * BATCH * (DIM / 4);

    // ---- atomic-free bucketed partition + bucket-local sort -> CSR ----
    part_count<<<NPART, 256, 0, stream>>>(row, hcnt);
    part_scanA<<<(NB + 3) / 4, 256, 0, stream>>>(hcnt, bcnt);
    part_scanB<<<1, 1024, 0, stream>>>(bcnt, bptr, rowptr);
    part_scatter<<<NPART, 256, 0, stream>>>(row, col, vals, hcnt, bptr, cvtmp);
    bucket_sort<<<NB, 256, 0, stream>>>(bptr, (const long long*)cvtmp, cv, rowptr);

    // ---- layer-0 embedding + batch accumulator init ----
    concat_init<<<(node_v4 + 255) / 256, 256, 0, stream>>>(
        (const float4*)uw, (const float4*)iw, (const float4*)tw, (float4*)A);
    batch_init<<<(batch_v4 + 255) / 256, 256, 0, stream>>>(
        (const float4*)uw, (const float4*)iw, users, items, (float4*)ACCB);

    // ---- layers 1,2: full SpMM; layer 3: batch rows only ----
    const int spmm_blocks = (N_NODES + 3) / 4;   // 4 row-waves per 256-block
    spmm_csr<<<spmm_blocks, 256, 0, stream>>>(rowptr, cv, A, B);
    batch_add<<<(batch_v4 + 255) / 256, 256, 0, stream>>>(
        (const float4*)B, users, items, (float4*)ACCB);
    spmm_csr<<<spmm_blocks, 256, 0, stream>>>(rowptr, cv, B, A);
    batch_add<<<(batch_v4 + 255) / 256, 256, 0, stream>>>(
        (const float4*)A, users, items, (float4*)ACCB);
    spmm_batch<<<(2 * BATCH + 3) / 4, 256, 0, stream>>>(
        rowptr, cv, A, users, items, ACCB);

    final_dot<<<(BATCH + 3) / 4, 256, 0, stream>>>(ACCB, out);
}